// Round 5
// baseline (1371.673 us; speedup 1.0000x reference)
//
#include <hip/hip_runtime.h>
#include <cfloat>

// NearestNeighborGraph: S=16, N=2048, D=64, K=16.
// Round-5:
//  - amdgpu_waves_per_eu(2,2): rounds 3/4 capped at 128 VGPR because the
//    backend budgets for LDS-achievable occupancy (57KB -> 2 blocks/CU -> 4
//    waves/EU -> 128). Explicit min=max=2 waves/EU forces a 256-VGPR budget;
//    grid is 1 block/CU anyway so no runtime occupancy loss.
//  - split j-feed: k[0,32) via LDS broadcast (8 ds_read_b128), k[32,64) via
//    wave-uniform global loads (SMEM/VMEM pipe) -- LDS pipe alone would cap
//    at ~164 us (32768 b128 x 12cyc per CU vs 55 us of fmac).
// d2 arithmetic bit-identical to rounds 1-4 (same chains, same x2 kernel).

constexpr int NS = 16, NP = 2048, ND = 64, KK = 16;
constexpr int NW  = 8;            // waves per block
constexpr int NT  = NW * 64;      // 512 threads
constexpr int JW  = NP / NW;      // 256 j per wave
constexpr int CH  = 4;            // j-rows per staged chunk (half-width: 128 floats)
constexpr int NCH = JW / CH;      // 64 chunks
constexpr int BUF = 4;            // candidate slots per lane per row
constexpr int MS  = 17;           // merge-tree stride (bank-conflict pad)

__global__ void x2_kernel(const float* __restrict__ h, float* __restrict__ x2)
{
    int g = blockIdx.x * 256 + threadIdx.x;          // 0 .. NS*NP-1
    const float4* row = (const float4*)(h + (size_t)g * ND);
    int ph = g & 15;                                  // == j&15 within sample
    float a0 = 0.f, a1 = 0.f, a2 = 0.f, a3 = 0.f;
    #pragma unroll
    for (int k = 0; k < 16; ++k) {
        float4 v = row[(k + ph) & 15];               // round-1's rotated order
        a0 = fmaf(v.x, v.x, a0); a1 = fmaf(v.y, v.y, a1);
        a2 = fmaf(v.z, v.z, a2); a3 = fmaf(v.w, v.w, a3);
    }
    x2[g] = (a0 + a1) + (a2 + a3);
}

__device__ __forceinline__ void insert16(float (&d)[KK], int (&ix)[KK],
                                         float v, int j)
{
    #pragma unroll
    for (int p = KK - 1; p > 0; --p) {
        bool sh = v < d[p - 1];
        bool he = v < d[p];
        float nd = sh ? d[p - 1] : (he ? v : d[p]);
        int   ni = sh ? ix[p - 1] : (he ? j : ix[p]);
        d[p] = nd; ix[p] = ni;
    }
    if (v < d[0]) { d[0] = v; ix[0] = j; }
}

// stable odd-even transposition sort (strict < keeps lower index first on ties)
__device__ __forceinline__ void sort16(float (&d)[KK], int (&ix)[KK])
{
    #pragma unroll
    for (int pass = 0; pass < KK; ++pass) {
        #pragma unroll
        for (int k = (pass & 1); k + 1 < KK; k += 2) {
            bool sw = d[k + 1] < d[k];
            float td = d[k];     int ti = ix[k];
            float tu = d[k + 1]; int tj = ix[k + 1];
            d[k]     = sw ? tu : td;  ix[k]     = sw ? tj : ti;
            d[k + 1] = sw ? td : tu;  ix[k + 1] = sw ? ti : tj;
        }
    }
}

// two dots: k-chunks 0..7 from LDS broadcast, 8..15 from wave-uniform global.
// fmaf chain order identical to rounds 1-4 -> bit-identical d2.
__device__ __forceinline__ void dot2_split(const float* __restrict__ lds_lo,
                                           const float4* __restrict__ g_hi,
                                           const float4 (&A)[16], const float4 (&B)[16],
                                           float& da, float& db)
{
    const float4* lo = (const float4*)lds_lo;
    float a0 = 0.f, a1 = 0.f, a2 = 0.f, a3 = 0.f;
    float b0 = 0.f, b1 = 0.f, b2 = 0.f, b3 = 0.f;
    #pragma unroll
    for (int k = 0; k < 8; ++k) {
        float4 c = lo[k];
        a0 = fmaf(A[k].x, c.x, a0); a1 = fmaf(A[k].y, c.y, a1);
        a2 = fmaf(A[k].z, c.z, a2); a3 = fmaf(A[k].w, c.w, a3);
        b0 = fmaf(B[k].x, c.x, b0); b1 = fmaf(B[k].y, c.y, b1);
        b2 = fmaf(B[k].z, c.z, b2); b3 = fmaf(B[k].w, c.w, b3);
    }
    #pragma unroll
    for (int k = 0; k < 8; ++k) {
        float4 c = g_hi[k];
        a0 = fmaf(A[8 + k].x, c.x, a0); a1 = fmaf(A[8 + k].y, c.y, a1);
        a2 = fmaf(A[8 + k].z, c.z, a2); a3 = fmaf(A[8 + k].w, c.w, a3);
        b0 = fmaf(B[8 + k].x, c.x, b0); b1 = fmaf(B[8 + k].y, c.y, b1);
        b2 = fmaf(B[8 + k].z, c.z, b2); b3 = fmaf(B[8 + k].w, c.w, b3);
    }
    da = (a0 + a1) + (a2 + a3);
    db = (b0 + b1) + (b2 + b3);
}

__attribute__((amdgpu_waves_per_eu(2, 2)))
__global__ __launch_bounds__(NT)
void knn_main(const float* __restrict__ h, const float* __restrict__ x2g,
              float* __restrict__ out)
{
    // LDS (floats): stage [0,2048) | x2 [2048,4096) | push-d [4096,8192) |
    // push-i [8192,12288) | merge tree (stride-17) aliases [4096,12800).
    __shared__ __align__(16) float smem[12800];      // 51200 B
    float* stage = smem;                   // 8 waves x 2 bufs x 128 (k-half)
    float* ldsx2 = smem + 2048;
    float* pbufd = smem + 4096;            // [2 rows][BUF][NT]
    int*   pbufi = (int*)(smem + 8192);

    const int t  = threadIdx.x;
    const int ln = t & 63;
    const int q  = t >> 6;                 // wave id = j-eighth
    const int s  = blockIdx.x >> 4;
    const int rb = blockIdx.x & 15;
    const int rowA = rb * 128 + ln;
    const int rowB = rowA + 64;
    const float* __restrict__ hs = h + (size_t)s * NP * ND;

    // stage the sample's x2 (broadcast-readable later)
    for (int i = t; i < NP; i += NT) ldsx2[i] = x2g[s * NP + i];

    // own rows into registers (128 VGPRs)
    float4 A[16], B[16];
    {
        const float4* ra = (const float4*)(hs + rowA * ND);
        const float4* rp = (const float4*)(hs + rowB * ND);
        #pragma unroll
        for (int k = 0; k < 16; ++k) { A[k] = ra[k]; B[k] = rp[k]; }
    }
    float x2A, x2B;
    {
        float a0 = 0.f, a1 = 0.f, a2 = 0.f, a3 = 0.f;
        #pragma unroll
        for (int k = 0; k < 16; ++k) {
            a0 = fmaf(A[k].x, A[k].x, a0); a1 = fmaf(A[k].y, A[k].y, a1);
            a2 = fmaf(A[k].z, A[k].z, a2); a3 = fmaf(A[k].w, A[k].w, a3);
        }
        x2A = (a0 + a1) + (a2 + a3);
    }
    {
        float a0 = 0.f, a1 = 0.f, a2 = 0.f, a3 = 0.f;
        #pragma unroll
        for (int k = 0; k < 16; ++k) {
            a0 = fmaf(B[k].x, B[k].x, a0); a1 = fmaf(B[k].y, B[k].y, a1);
            a2 = fmaf(B[k].z, B[k].z, a2); a3 = fmaf(B[k].w, B[k].w, a3);
        }
        x2B = (a0 + a1) + (a2 + a3);
    }

    const int jbase = q * JW;
    float* stW = stage + q * 256;          // wave-private: 2 bufs x 128 floats
    // staging source: lane ln carries float2 (ln&15)*2 of row jbase+(ln>>4)+4c
    const float* gst  = hs + (size_t)(jbase + (ln >> 4)) * ND + (ln & 15) * 2;
    const int stOff   = (ln >> 4) * 32 + (ln & 15) * 2;

    // prologue: chunk 0 -> buf0, chunk 1 in flight
    float2 v0 = *(const float2*)(gst);
    *(float2*)(stW + stOff) = v0;
    float2 vn = *(const float2*)(gst + CH * ND);

    __syncthreads();   // x2 staging visible (stage itself is wave-private)

    float distA[KK], distB[KK];
    int   idxA[KK],  idxB[KK];

    // ---- peel: first 16 j -> direct stores, then stable sort ----
    #pragma unroll
    for (int c = 0; c < 4; ++c) {
        const float4 xc = ((const float4*)ldsx2)[(jbase >> 2) + c];
        const float* bufp = stW + (c & 1) * 128;
        #pragma unroll
        for (int jj = 0; jj < CH; ++jj) {
            const int j = jbase + c * CH + jj;
            const float4* ghi = (const float4*)(hs + (size_t)j * ND + 32);
            float da, db;
            dot2_split(bufp + jj * 32, ghi, A, B, da, db);
            float xj = (jj == 0) ? xc.x : (jj == 1) ? xc.y : (jj == 2) ? xc.z : xc.w;
            distA[c * CH + jj] = fmaf(-2.f, da, x2A + xj);
            distB[c * CH + jj] = fmaf(-2.f, db, x2B + xj);
            idxA[c * CH + jj] = j;
            idxB[c * CH + jj] = j;
        }
        *(float2*)(stW + ((c + 1) & 1) * 128 + stOff) = vn;
        int nc = (c + 2 < NCH) ? (c + 2) : (NCH - 1);
        vn = *(const float2*)(gst + (size_t)nc * CH * ND);
    }
    sort16(distA, idxA);
    sort16(distB, idxB);

    int cntA = 0, cntB = 0;
    auto drain = [&]() {
        #pragma unroll 1
        for (int k = 0; k < BUF; ++k) {
            if (!__any((k < cntA) | (k < cntB))) break;
            float da = pbufd[k * NT + t];         int ja = pbufi[k * NT + t];
            insert16(distA, idxA, (k < cntA) ? da : FLT_MAX, ja);
            float db = pbufd[(BUF + k) * NT + t]; int jb = pbufi[(BUF + k) * NT + t];
            insert16(distB, idxB, (k < cntB) ? db : FLT_MAX, jb);
        }
        cntA = 0; cntB = 0;
    };

    // ---- main loop: chunks 4..63, barrier-free double-buffered staging ----
    for (int c = 4; c < NCH; ++c) {
        const float4 xc = ((const float4*)ldsx2)[(jbase >> 2) + c];
        const float* bufp = stW + (c & 1) * 128;
        #pragma unroll
        for (int jj = 0; jj < CH; ++jj) {
            const int j = jbase + c * CH + jj;
            const float4* ghi = (const float4*)(hs + (size_t)j * ND + 32);
            float da, db;
            dot2_split(bufp + jj * 32, ghi, A, B, da, db);
            float xj = (jj == 0) ? xc.x : (jj == 1) ? xc.y : (jj == 2) ? xc.z : xc.w;
            float d2a = fmaf(-2.f, da, x2A + xj);
            float d2b = fmaf(-2.f, db, x2B + xj);
            pbufd[cntA * NT + t] = d2a;          pbufi[cntA * NT + t] = j;
            cntA += (d2a < distA[KK - 1]) ? 1 : 0;
            pbufd[(BUF + cntB) * NT + t] = d2b;  pbufi[(BUF + cntB) * NT + t] = j;
            cntB += (d2b < distB[KK - 1]) ? 1 : 0;
            if (__any((cntA == BUF) | (cntB == BUF))) drain();
        }
        if (c + 1 < NCH) *(float2*)(stW + ((c + 1) & 1) * 128 + stOff) = vn;
        if (c + 2 < NCH) vn = *(const float2*)(gst + (size_t)(c + 2) * CH * ND);
    }
    drain();

    // ---- 3-level merge tree through LDS (stride-17; aliases dead push bufs) ----
    __syncthreads();
    float* md = smem + 4096;               // 4 regions x 64 lanes, stride MS
    int*   mi = (int*)(smem + 4096 + 4352);
    #pragma unroll 1
    for (int lvl = 0; lvl < 3; ++lvl) {
        const int step = 1 << lvl;
        const int m    = (step << 1) - 1;
        const bool pub = (q & m) == step;
        const bool con = (q & m) == 0;
        const int reg  = q >> (lvl + 1);
        if (pub) {
            #pragma unroll
            for (int k = 0; k < KK; ++k) {
                md[(reg * 64 + ln) * MS + k] = distA[k];
                mi[(reg * 64 + ln) * MS + k] = idxA[k];
            }
        }
        __syncthreads();
        if (con) {
            #pragma unroll 1
            for (int k = 0; k < KK; ++k)
                insert16(distA, idxA, md[(reg * 64 + ln) * MS + k],
                                      mi[(reg * 64 + ln) * MS + k]);
        }
        __syncthreads();
        if (pub) {
            #pragma unroll
            for (int k = 0; k < KK; ++k) {
                md[(reg * 64 + ln) * MS + k] = distB[k];
                mi[(reg * 64 + ln) * MS + k] = idxB[k];
            }
        }
        __syncthreads();
        if (con) {
            #pragma unroll 1
            for (int k = 0; k < KK; ++k)
                insert16(distB, idxB, md[(reg * 64 + ln) * MS + k],
                                      mi[(reg * 64 + ln) * MS + k]);
        }
        __syncthreads();
    }

    // ---- output (wave 0 holds the complete lists for rows rowA, rowB) ----
    if (q == 0) {
        const int off = s * NP;
        {
            const size_t rg = (size_t)off + rowA;
            float* o0 = out + rg * KK;
            float* o1 = out + (size_t)NS * NP * KK + rg * KK;
            float* o2 = out + (size_t)2 * NS * NP * KK + rg * KK;
            #pragma unroll
            for (int k = 0; k < KK; ++k) o0[k] = distA[k];
            #pragma unroll
            for (int k = 0; k < KK; ++k) o1[k] = (float)(idxA[k] + off);
            #pragma unroll
            for (int k = 0; k < KK; ++k) o2[k] = (float)(off + rowA);
        }
        {
            const size_t rg = (size_t)off + rowB;
            float* o0 = out + rg * KK;
            float* o1 = out + (size_t)NS * NP * KK + rg * KK;
            float* o2 = out + (size_t)2 * NS * NP * KK + rg * KK;
            #pragma unroll
            for (int k = 0; k < KK; ++k) o0[k] = distB[k];
            #pragma unroll
            for (int k = 0; k < KK; ++k) o1[k] = (float)(idxB[k] + off);
            #pragma unroll
            for (int k = 0; k < KK; ++k) o2[k] = (float)(off + rowB);
        }
    }
}

extern "C" void kernel_launch(void* const* d_in, const int* in_sizes, int n_in,
                              void* d_out, int out_size, void* d_ws, size_t ws_size,
                              hipStream_t stream)
{
    const float* h = (const float*)d_in[0];
    float* x2  = (float*)d_ws;            // NS*NP floats = 128 KB scratch
    float* out = (float*)d_out;
    hipLaunchKernelGGL(x2_kernel, dim3(NS * NP / 256), dim3(256), 0, stream, h, x2);
    hipLaunchKernelGGL(knn_main,  dim3(NS * 16),       dim3(NT),  0, stream, h, x2, out);
}

// Round 6
// 358.238 us; speedup vs baseline: 3.8289x; 3.8289x over previous
//
#include <hip/hip_runtime.h>
#include <cfloat>

// NearestNeighborGraph: S=16, N=2048, D=64, K=16.
// Round-6 = round-2 skeleton (1 i-row/lane, wave-uniform s_load feed, LDS
// push-buffer + wave drains) with the latency fixed:
//  - 512-thread blocks (8 waves, each a 256-j eighth), grid 512 -> 2 blocks/CU
//    = 4 waves/SIMD (round 2 had only 2, grid-limited) -> scalar-load latency
//    hidden by 3 co-resident waves.
//  - software-pipelined prefetch of next-j's first 16-float chunk (~192-cyc
//    distance), wrap-masked to stay in range.
//  - live state ~110 VGPR: under the 128 cap the backend enforces for
//    512-thread blocks (rounds 3-5 proved 2-rows/lane cannot fit).
// d2 arithmetic bit-identical to rounds 1-5 (same chains, same x2 kernel).

typedef float f16v __attribute__((ext_vector_type(16)));

constexpr int NS = 16, NP = 2048, ND = 64, KK = 16;
constexpr int NW  = 8;            // waves per block
constexpr int NT  = NW * 64;      // 512 threads
constexpr int JW  = NP / NW;      // 256 j per wave
constexpr int BUF = 8;            // candidate slots per lane
constexpr int MS  = 17;           // merge-tree stride (bank-conflict pad)

__global__ void x2_kernel(const float* __restrict__ h, float* __restrict__ x2)
{
    int g = blockIdx.x * 256 + threadIdx.x;          // 0 .. NS*NP-1
    const float4* row = (const float4*)(h + (size_t)g * ND);
    int ph = g & 15;                                  // == j&15 within sample
    float a0 = 0.f, a1 = 0.f, a2 = 0.f, a3 = 0.f;
    #pragma unroll
    for (int k = 0; k < 16; ++k) {
        float4 v = row[(k + ph) & 15];               // round-1's rotated order
        a0 = fmaf(v.x, v.x, a0); a1 = fmaf(v.y, v.y, a1);
        a2 = fmaf(v.z, v.z, a2); a3 = fmaf(v.w, v.w, a3);
    }
    x2[g] = (a0 + a1) + (a2 + a3);
}

__device__ __forceinline__ void insert16(float (&d)[KK], int (&ix)[KK],
                                         float v, int j)
{
    #pragma unroll
    for (int p = KK - 1; p > 0; --p) {
        bool sh = v < d[p - 1];
        bool he = v < d[p];
        float nd = sh ? d[p - 1] : (he ? v : d[p]);
        int   ni = sh ? ix[p - 1] : (he ? j : ix[p]);
        d[p] = nd; ix[p] = ni;
    }
    if (v < d[0]) { d[0] = v; ix[0] = j; }
}

__global__ __launch_bounds__(NT)
void knn_main(const float* __restrict__ h, const float* __restrict__ x2g,
              float* __restrict__ out)
{
    // LDS: push-d [0,4096) | push-i [4096,8192) floats (32 KB).
    // merge tree (stride-17): md [0,4352) | mi [4352,8704) -- aliases the
    // dead push region after the final drain (barrier-separated).
    __shared__ __align__(16) float smem[8704];       // 34816 B -> 2+ blocks/CU
    float* pbufd = smem;
    int*   pbufi = (int*)(smem + 4096);

    const int t  = threadIdx.x;
    const int ln = t & 63;
    const int q  = t >> 6;                 // wave id = j-eighth
    const int s  = blockIdx.x >> 5;
    const int rb = blockIdx.x & 31;
    const int row = rb * 64 + ln;          // lane's i-row
    const float* __restrict__ hs = h + (size_t)s * NP * ND;

    // own row into registers (64 VGPRs)
    float4 A[16];
    {
        const float4* ra = (const float4*)(hs + row * ND);
        #pragma unroll
        for (int k = 0; k < 16; ++k) A[k] = ra[k];
    }
    float x2i;
    {
        float a0 = 0.f, a1 = 0.f, a2 = 0.f, a3 = 0.f;
        #pragma unroll
        for (int k = 0; k < 16; ++k) {
            a0 = fmaf(A[k].x, A[k].x, a0); a1 = fmaf(A[k].y, A[k].y, a1);
            a2 = fmaf(A[k].z, A[k].z, a2); a3 = fmaf(A[k].w, A[k].w, a3);
        }
        x2i = (a0 + a1) + (a2 + a3);
    }

    float dist[KK]; int idx[KK];
    #pragma unroll
    for (int k = 0; k < KK; ++k) { dist[k] = FLT_MAX; idx[k] = 0; }

    // wave-uniform (scalar) feed bases
    const int jbase = __builtin_amdgcn_readfirstlane(q * JW);
    const f16v*  __restrict__ hq  = (const f16v*)(hs + (size_t)jbase * ND);
    const float* __restrict__ x2q = x2g + s * NP + jbase;

    int cnt = 0;
    auto drain = [&]() {
        #pragma unroll 1
        for (int k = 0; k < BUF; ++k) {
            if (!__any(k < cnt)) break;
            bool  act = k < cnt;
            float dd  = pbufd[k * NT + t];
            int   dj  = pbufi[k * NT + t];
            insert16(dist, idx, act ? dd : FLT_MAX, dj);
        }
        cnt = 0;
    };

    // prefetch: chunk 0 of j=0
    f16v n0 = hq[0];

    for (int jj = 0; jj < JW; ++jj) {
        const f16v c0 = n0;
        const f16v c1 = hq[jj * 4 + 1];
        const f16v c2 = hq[jj * 4 + 2];
        const f16v c3 = hq[jj * 4 + 3];
        const float x2j = x2q[jj];

        float a0 = 0.f, a1 = 0.f, a2 = 0.f, a3 = 0.f;
        #pragma unroll
        for (int k = 0; k < 4; ++k) {
            a0 = fmaf(A[k].x, c0[4 * k + 0], a0);
            a1 = fmaf(A[k].y, c0[4 * k + 1], a1);
            a2 = fmaf(A[k].z, c0[4 * k + 2], a2);
            a3 = fmaf(A[k].w, c0[4 * k + 3], a3);
        }
        // prefetch next j's first chunk (~192-cyc distance); wrap to stay
        // in-range at jj=JW-1 (value unused next iteration start... reloaded)
        n0 = hq[((jj + 1) & (JW - 1)) * 4];
        #pragma unroll
        for (int k = 0; k < 4; ++k) {
            a0 = fmaf(A[4 + k].x, c1[4 * k + 0], a0);
            a1 = fmaf(A[4 + k].y, c1[4 * k + 1], a1);
            a2 = fmaf(A[4 + k].z, c1[4 * k + 2], a2);
            a3 = fmaf(A[4 + k].w, c1[4 * k + 3], a3);
        }
        #pragma unroll
        for (int k = 0; k < 4; ++k) {
            a0 = fmaf(A[8 + k].x, c2[4 * k + 0], a0);
            a1 = fmaf(A[8 + k].y, c2[4 * k + 1], a1);
            a2 = fmaf(A[8 + k].z, c2[4 * k + 2], a2);
            a3 = fmaf(A[8 + k].w, c2[4 * k + 3], a3);
        }
        #pragma unroll
        for (int k = 0; k < 4; ++k) {
            a0 = fmaf(A[12 + k].x, c3[4 * k + 0], a0);
            a1 = fmaf(A[12 + k].y, c3[4 * k + 1], a1);
            a2 = fmaf(A[12 + k].z, c3[4 * k + 2], a2);
            a3 = fmaf(A[12 + k].w, c3[4 * k + 3], a3);
        }
        float dotv = (a0 + a1) + (a2 + a3);
        float d2 = fmaf(-2.0f, dotv, x2i + x2j);

        // branch-free push: always write slot cnt, bump cnt only on hit
        pbufd[cnt * NT + t] = d2;
        pbufi[cnt * NT + t] = jbase + jj;
        cnt += (d2 < dist[KK - 1]) ? 1 : 0;
        if (__any(cnt == BUF)) drain();
    }
    drain();

    // ---- 3-level merge tree through LDS (stride-17; aliases push bufs) ----
    __syncthreads();
    float* md = smem;                      // 4 regions x 64 lanes, stride MS
    int*   mi = (int*)(smem + 4352);
    #pragma unroll 1
    for (int lvl = 0; lvl < 3; ++lvl) {
        const int step = 1 << lvl;
        const int m    = (step << 1) - 1;
        const bool pub = (q & m) == step;
        const bool con = (q & m) == 0;
        const int reg  = q >> (lvl + 1);
        if (pub) {
            #pragma unroll
            for (int k = 0; k < KK; ++k) {
                md[(reg * 64 + ln) * MS + k] = dist[k];
                mi[(reg * 64 + ln) * MS + k] = idx[k];
            }
        }
        __syncthreads();
        if (con) {
            #pragma unroll 1
            for (int k = 0; k < KK; ++k)
                insert16(dist, idx, md[(reg * 64 + ln) * MS + k],
                                    mi[(reg * 64 + ln) * MS + k]);
        }
        __syncthreads();
    }

    // ---- output (wave 0 holds the complete list for its 64 rows) ----
    if (q == 0) {
        const int off = s * NP;
        const size_t rg = (size_t)off + row;
        float* o0 = out + rg * KK;
        float* o1 = out + (size_t)NS * NP * KK + rg * KK;
        float* o2 = out + (size_t)2 * NS * NP * KK + rg * KK;
        #pragma unroll
        for (int k = 0; k < KK; ++k) o0[k] = dist[k];
        #pragma unroll
        for (int k = 0; k < KK; ++k) o1[k] = (float)(idx[k] + off);
        #pragma unroll
        for (int k = 0; k < KK; ++k) o2[k] = (float)(off + row);
    }
}

extern "C" void kernel_launch(void* const* d_in, const int* in_sizes, int n_in,
                              void* d_out, int out_size, void* d_ws, size_t ws_size,
                              hipStream_t stream)
{
    const float* h = (const float*)d_in[0];
    float* x2  = (float*)d_ws;            // NS*NP floats = 128 KB scratch
    float* out = (float*)d_out;
    hipLaunchKernelGGL(x2_kernel, dim3(NS * NP / 256), dim3(256), 0, stream, h, x2);
    hipLaunchKernelGGL(knn_main,  dim3(NS * 32),       dim3(NT),  0, stream, h, x2, out);
}

// Round 7
// 355.753 us; speedup vs baseline: 3.8557x; 1.0070x over previous
//
#include <hip/hip_runtime.h>
#include <cfloat>

// NearestNeighborGraph: S=16, N=2048, D=64, K=16.
// Round-7 = round-6 skeleton with occupancy doubled:
//  - j-range split across 2 blocks (each 1024 j; waves take 128 j) -> grid
//    1024 blocks = 4 blocks/CU = up to 32 waves/CU (round 6 was grid-limited
//    to 16). Covers the per-iteration lgkmcnt(0) scalar-feed drain that held
//    VALUBusy at 46%.
//  - per-half top-16 lists -> d_ws; tiny merge kernel (strict < insert of the
//    higher-j half) produces exact round-6 results. Fallback to the direct
//    single-block-per-row path if ws_size is too small.
//  - dropped the n0 prefetch (lgkmcnt(0) drains made it dead weight).
// d2 arithmetic bit-identical to rounds 1-6 (same chains, same x2 kernel).

typedef float f16v __attribute__((ext_vector_type(16)));

constexpr int NS = 16, NP = 2048, ND = 64, KK = 16;
constexpr int NW  = 8;            // waves per block
constexpr int NT  = NW * 64;      // 512 threads
constexpr int BUF = 8;            // candidate slots per lane
constexpr int MS  = 17;           // merge-tree stride (bank-conflict pad)

__global__ void x2_kernel(const float* __restrict__ h, float* __restrict__ x2)
{
    int g = blockIdx.x * 256 + threadIdx.x;          // 0 .. NS*NP-1
    const float4* row = (const float4*)(h + (size_t)g * ND);
    int ph = g & 15;                                  // == j&15 within sample
    float a0 = 0.f, a1 = 0.f, a2 = 0.f, a3 = 0.f;
    #pragma unroll
    for (int k = 0; k < 16; ++k) {
        float4 v = row[(k + ph) & 15];               // round-1's rotated order
        a0 = fmaf(v.x, v.x, a0); a1 = fmaf(v.y, v.y, a1);
        a2 = fmaf(v.z, v.z, a2); a3 = fmaf(v.w, v.w, a3);
    }
    x2[g] = (a0 + a1) + (a2 + a3);
}

__device__ __forceinline__ void insert16(float (&d)[KK], int (&ix)[KK],
                                         float v, int j)
{
    #pragma unroll
    for (int p = KK - 1; p > 0; --p) {
        bool sh = v < d[p - 1];
        bool he = v < d[p];
        float nd = sh ? d[p - 1] : (he ? v : d[p]);
        int   ni = sh ? ix[p - 1] : (he ? j : ix[p]);
        d[p] = nd; ix[p] = ni;
    }
    if (v < d[0]) { d[0] = v; ix[0] = j; }
}

// JWT = j's per wave; SPLIT = NP/(NW*JWT) blocks per row-group.
template<int JWT, bool DIRECT>
__global__ __launch_bounds__(NT)
void knn_main(const float* __restrict__ h, const float* __restrict__ x2g,
              float* __restrict__ out, float* __restrict__ wsD,
              int* __restrict__ wsI)
{
    constexpr int SPLIT = NP / (NW * JWT);
    // LDS: push-d [0,4096) | push-i [4096,8192) floats (32 KB).
    // merge tree (stride-17) aliases: md [0,4352) | mi [4352,8704).
    __shared__ __align__(16) float smem[8704];       // 34816 B
    float* pbufd = smem;
    int*   pbufi = (int*)(smem + 4096);

    const int t  = threadIdx.x;
    const int ln = t & 63;
    const int q  = t >> 6;                 // wave id within block
    const int b  = blockIdx.x;
    const int s    = b / (32 * SPLIT);
    const int rem  = b - s * (32 * SPLIT);
    const int rb   = rem / SPLIT;
    const int half = rem - rb * SPLIT;     // which j-half this block scans
    const int row  = rb * 64 + ln;         // lane's i-row
    const float* __restrict__ hs = h + (size_t)s * NP * ND;

    // own row into registers
    float4 A[16];
    {
        const float4* ra = (const float4*)(hs + row * ND);
        #pragma unroll
        for (int k = 0; k < 16; ++k) A[k] = ra[k];
    }
    float x2i;
    {
        float a0 = 0.f, a1 = 0.f, a2 = 0.f, a3 = 0.f;
        #pragma unroll
        for (int k = 0; k < 16; ++k) {
            a0 = fmaf(A[k].x, A[k].x, a0); a1 = fmaf(A[k].y, A[k].y, a1);
            a2 = fmaf(A[k].z, A[k].z, a2); a3 = fmaf(A[k].w, A[k].w, a3);
        }
        x2i = (a0 + a1) + (a2 + a3);
    }

    float dist[KK]; int idx[KK];
    #pragma unroll
    for (int k = 0; k < KK; ++k) { dist[k] = FLT_MAX; idx[k] = 0; }

    // wave-uniform (scalar) feed bases
    const int jbase = __builtin_amdgcn_readfirstlane(half * (NW * JWT) + q * JWT);
    const f16v*  __restrict__ hq  = (const f16v*)(hs + (size_t)jbase * ND);
    const float* __restrict__ x2q = x2g + s * NP + jbase;

    int cnt = 0;
    auto drain = [&]() {
        #pragma unroll 1
        for (int k = 0; k < BUF; ++k) {
            if (!__any(k < cnt)) break;
            bool  act = k < cnt;
            float dd  = pbufd[k * NT + t];
            int   dj  = pbufi[k * NT + t];
            insert16(dist, idx, act ? dd : FLT_MAX, dj);
        }
        cnt = 0;
    };

    for (int jj = 0; jj < JWT; ++jj) {
        const f16v c0 = hq[jj * 4 + 0];
        const f16v c1 = hq[jj * 4 + 1];
        const f16v c2 = hq[jj * 4 + 2];
        const f16v c3 = hq[jj * 4 + 3];
        const float x2j = x2q[jj];

        float a0 = 0.f, a1 = 0.f, a2 = 0.f, a3 = 0.f;
        #pragma unroll
        for (int k = 0; k < 4; ++k) {
            a0 = fmaf(A[k].x, c0[4 * k + 0], a0);
            a1 = fmaf(A[k].y, c0[4 * k + 1], a1);
            a2 = fmaf(A[k].z, c0[4 * k + 2], a2);
            a3 = fmaf(A[k].w, c0[4 * k + 3], a3);
        }
        #pragma unroll
        for (int k = 0; k < 4; ++k) {
            a0 = fmaf(A[4 + k].x, c1[4 * k + 0], a0);
            a1 = fmaf(A[4 + k].y, c1[4 * k + 1], a1);
            a2 = fmaf(A[4 + k].z, c1[4 * k + 2], a2);
            a3 = fmaf(A[4 + k].w, c1[4 * k + 3], a3);
        }
        #pragma unroll
        for (int k = 0; k < 4; ++k) {
            a0 = fmaf(A[8 + k].x, c2[4 * k + 0], a0);
            a1 = fmaf(A[8 + k].y, c2[4 * k + 1], a1);
            a2 = fmaf(A[8 + k].z, c2[4 * k + 2], a2);
            a3 = fmaf(A[8 + k].w, c2[4 * k + 3], a3);
        }
        #pragma unroll
        for (int k = 0; k < 4; ++k) {
            a0 = fmaf(A[12 + k].x, c3[4 * k + 0], a0);
            a1 = fmaf(A[12 + k].y, c3[4 * k + 1], a1);
            a2 = fmaf(A[12 + k].z, c3[4 * k + 2], a2);
            a3 = fmaf(A[12 + k].w, c3[4 * k + 3], a3);
        }
        float dotv = (a0 + a1) + (a2 + a3);
        float d2 = fmaf(-2.0f, dotv, x2i + x2j);

        // branch-free push: always write slot cnt, bump cnt only on hit
        pbufd[cnt * NT + t] = d2;
        pbufi[cnt * NT + t] = jbase + jj;
        cnt += (d2 < dist[KK - 1]) ? 1 : 0;
        if (__any(cnt == BUF)) drain();
    }
    drain();

    // ---- 3-level merge tree through LDS (stride-17; aliases push bufs) ----
    __syncthreads();
    float* md = smem;                      // 4 regions x 64 lanes, stride MS
    int*   mi = (int*)(smem + 4352);
    #pragma unroll 1
    for (int lvl = 0; lvl < 3; ++lvl) {
        const int step = 1 << lvl;
        const int m    = (step << 1) - 1;
        const bool pub = (q & m) == step;
        const bool con = (q & m) == 0;
        const int reg  = q >> (lvl + 1);
        if (pub) {
            #pragma unroll
            for (int k = 0; k < KK; ++k) {
                md[(reg * 64 + ln) * MS + k] = dist[k];
                mi[(reg * 64 + ln) * MS + k] = idx[k];
            }
        }
        __syncthreads();
        if (con) {
            #pragma unroll 1
            for (int k = 0; k < KK; ++k)
                insert16(dist, idx, md[(reg * 64 + ln) * MS + k],
                                    mi[(reg * 64 + ln) * MS + k]);
        }
        __syncthreads();
    }

    // ---- emit (wave 0 holds the block's complete per-half lists) ----
    if (q == 0) {
        if (DIRECT) {
            const int off = s * NP;
            const size_t rg = (size_t)off + row;
            float* o0 = out + rg * KK;
            float* o1 = out + (size_t)NS * NP * KK + rg * KK;
            float* o2 = out + (size_t)2 * NS * NP * KK + rg * KK;
            #pragma unroll
            for (int k = 0; k < KK; ++k) o0[k] = dist[k];
            #pragma unroll
            for (int k = 0; k < KK; ++k) o1[k] = (float)(idx[k] + off);
            #pragma unroll
            for (int k = 0; k < KK; ++k) o2[k] = (float)(off + row);
        } else {
            const size_t slot = ((size_t)(s * NP + row) * SPLIT + half) * KK;
            #pragma unroll
            for (int k = 0; k < KK; ++k) wsD[slot + k] = dist[k];
            #pragma unroll
            for (int k = 0; k < KK; ++k) wsI[slot + k] = idx[k];
        }
    }
}

// merge the two j-half lists per row (half A = lower j; strict < keeps
// the lowest-index-first tie-break) and emit the outputs.
__global__ void merge_kernel(const float* __restrict__ wsD,
                             const int* __restrict__ wsI,
                             float* __restrict__ out)
{
    const int g = blockIdx.x * 256 + threadIdx.x;    // 0 .. NS*NP-1
    float dist[KK]; int idx[KK];
    const size_t s0 = (size_t)g * 2 * KK;
    #pragma unroll
    for (int k = 0; k < KK; ++k) { dist[k] = wsD[s0 + k]; idx[k] = wsI[s0 + k]; }
    #pragma unroll 1
    for (int k = 0; k < KK; ++k)
        insert16(dist, idx, wsD[s0 + KK + k], wsI[s0 + KK + k]);

    const int s = g >> 11;                           // g / NP
    const int off = s * NP;
    float* o0 = out + (size_t)g * KK;
    float* o1 = out + (size_t)NS * NP * KK + (size_t)g * KK;
    float* o2 = out + (size_t)2 * NS * NP * KK + (size_t)g * KK;
    #pragma unroll
    for (int k = 0; k < KK; ++k) o0[k] = dist[k];
    #pragma unroll
    for (int k = 0; k < KK; ++k) o1[k] = (float)(idx[k] + off);
    #pragma unroll
    for (int k = 0; k < KK; ++k) o2[k] = (float)(g);
}

extern "C" void kernel_launch(void* const* d_in, const int* in_sizes, int n_in,
                              void* d_out, int out_size, void* d_ws, size_t ws_size,
                              hipStream_t stream)
{
    const float* h = (const float*)d_in[0];
    float* out = (float*)d_out;
    float* x2  = (float*)d_ws;                       // 32768 floats = 128 KB
    float* wsD = x2 + 32768;                         // NS*NP*2*KK floats (4 MB)
    int*   wsI = (int*)(wsD + (size_t)NS * NP * 2 * KK);   // another 4 MB
    const size_t need = (32768 + (size_t)NS * NP * 2 * KK * 2) * 4;

    hipLaunchKernelGGL(x2_kernel, dim3(NS * NP / 256), dim3(256), 0, stream, h, x2);
    if (ws_size >= need) {
        hipLaunchKernelGGL((knn_main<128, false>), dim3(NS * 64), dim3(NT),
                           0, stream, h, x2, out, wsD, wsI);
        hipLaunchKernelGGL(merge_kernel, dim3(NS * NP / 256), dim3(256),
                           0, stream, wsD, wsI, out);
    } else {
        hipLaunchKernelGGL((knn_main<256, true>), dim3(NS * 32), dim3(NT),
                           0, stream, h, x2, out, nullptr, nullptr);
    }
}

// Round 8
// 330.130 us; speedup vs baseline: 4.1550x; 1.0776x over previous
//
#include <hip/hip_runtime.h>
#include <cfloat>

// NearestNeighborGraph: S=16, N=2048, D=64, K=16.
// Round-8:
//  - feed via lane-split global_load_dwordx4 (1 chunk = 4 j-rows per wave,
//    double-buffered in 8 VGPRs) + v_readlane broadcast into the fmac chains.
//    VMEM is vmcnt-tracked IN-ORDER -> fine-grained waits; kills the
//    per-iteration s_waitcnt lgkmcnt(0) drain that capped round 6/7 at ~62%
//    VALUBusy (SMEM returns out-of-order -> lgkmcnt(0) only).
//  - shared per-row threshold in LDS (any wave's dist[15] is a valid upper
//    bound on the row's global 16th distance; min-races are conservative) +
//    peel-16+sort bootstrap -> insert/drain work collapses ~4x.
//  - back to 512 blocks (8 waves x 256 j), direct output, no merge kernel.
// d2 arithmetic bit-identical to rounds 1-7 (same chains, same x2 kernel).

constexpr int NS = 16, NP = 2048, ND = 64, KK = 16;
constexpr int NW  = 8;            // waves per block
constexpr int NT  = NW * 64;      // 512 threads
constexpr int JW  = NP / NW;      // 256 j per wave
constexpr int NCH = JW / 4;       // 64 chunks of 4 j
constexpr int BUF = 8;            // candidate slots per lane
constexpr int MS  = 17;           // merge-tree stride (bank-conflict pad)

__global__ void x2_kernel(const float* __restrict__ h, float* __restrict__ x2)
{
    int g = blockIdx.x * 256 + threadIdx.x;          // 0 .. NS*NP-1
    const float4* row = (const float4*)(h + (size_t)g * ND);
    int ph = g & 15;                                  // == j&15 within sample
    float a0 = 0.f, a1 = 0.f, a2 = 0.f, a3 = 0.f;
    #pragma unroll
    for (int k = 0; k < 16; ++k) {
        float4 v = row[(k + ph) & 15];               // round-1's rotated order
        a0 = fmaf(v.x, v.x, a0); a1 = fmaf(v.y, v.y, a1);
        a2 = fmaf(v.z, v.z, a2); a3 = fmaf(v.w, v.w, a3);
    }
    x2[g] = (a0 + a1) + (a2 + a3);
}

__device__ __forceinline__ void insert16(float (&d)[KK], int (&ix)[KK],
                                         float v, int j)
{
    #pragma unroll
    for (int p = KK - 1; p > 0; --p) {
        bool sh = v < d[p - 1];
        bool he = v < d[p];
        float nd = sh ? d[p - 1] : (he ? v : d[p]);
        int   ni = sh ? ix[p - 1] : (he ? j : ix[p]);
        d[p] = nd; ix[p] = ni;
    }
    if (v < d[0]) { d[0] = v; ix[0] = j; }
}

// stable odd-even transposition sort (strict < keeps lower index first on ties)
__device__ __forceinline__ void sort16(float (&d)[KK], int (&ix)[KK])
{
    #pragma unroll
    for (int pass = 0; pass < KK; ++pass) {
        #pragma unroll
        for (int k = (pass & 1); k + 1 < KK; k += 2) {
            bool sw = d[k + 1] < d[k];
            float td = d[k];     int ti = ix[k];
            float tu = d[k + 1]; int tj = ix[k + 1];
            d[k]     = sw ? tu : td;  ix[k]     = sw ? tj : ti;
            d[k + 1] = sw ? td : tu;  ix[k + 1] = sw ? ti : tj;
        }
    }
}

__device__ __forceinline__ float rlane(float v, int l)
{
    return __uint_as_float((unsigned)__builtin_amdgcn_readlane(
        (int)__float_as_uint(v), l));
}

// dot of lane's own row A against broadcast row j held across lanes
// [Lb..Lb+15] of buf (lane Lb+k holds floats 4k..4k+3 of row j).
// chain order identical to rounds 1-7 -> bit-identical d2.
__device__ __forceinline__ float dotj(const float4 b, int Lb,
                                      const float4 (&A)[16])
{
    float a0 = 0.f, a1 = 0.f, a2 = 0.f, a3 = 0.f;
    #pragma unroll
    for (int k = 0; k < 16; ++k) {
        a0 = fmaf(A[k].x, rlane(b.x, Lb + k), a0);
        a1 = fmaf(A[k].y, rlane(b.y, Lb + k), a1);
        a2 = fmaf(A[k].z, rlane(b.z, Lb + k), a2);
        a3 = fmaf(A[k].w, rlane(b.w, Lb + k), a3);
    }
    return (a0 + a1) + (a2 + a3);
}

__global__ __launch_bounds__(NT)
void knn_main(const float* __restrict__ h, const float* __restrict__ x2g,
              float* __restrict__ out)
{
    // floats: merge tree [0,8704) (stride-17) aliases push-d [0,4096) +
    // push-i [4096,8192); x2 [8704,10752); thr [10752,10816).  43264 B.
    __shared__ __align__(16) float smem[10816];
    float* pbufd  = smem;
    int*   pbufi  = (int*)(smem + 4096);
    float* ldsx2  = smem + 8704;
    float* ldsthr = smem + 10752;

    const int t  = threadIdx.x;
    const int ln = t & 63;
    const int q  = t >> 6;                 // wave id = j-eighth
    const int s  = blockIdx.x >> 5;
    const int rb = blockIdx.x & 31;
    const int row = rb * 64 + ln;          // lane's i-row
    const float* __restrict__ hs = h + (size_t)s * NP * ND;

    // stage sample's x2 (coalesced float4) + init shared thresholds
    ((float4*)ldsx2)[t] = ((const float4*)(x2g + s * NP))[t];
    if (t < 64) ldsthr[t] = FLT_MAX;

    // own row into registers
    float4 A[16];
    {
        const float4* ra = (const float4*)(hs + (size_t)row * ND);
        #pragma unroll
        for (int k = 0; k < 16; ++k) A[k] = ra[k];
    }
    float x2i;
    {
        float a0 = 0.f, a1 = 0.f, a2 = 0.f, a3 = 0.f;
        #pragma unroll
        for (int k = 0; k < 16; ++k) {
            a0 = fmaf(A[k].x, A[k].x, a0); a1 = fmaf(A[k].y, A[k].y, a1);
            a2 = fmaf(A[k].z, A[k].z, a2); a3 = fmaf(A[k].w, A[k].w, a3);
        }
        x2i = (a0 + a1) + (a2 + a3);
    }

    __syncthreads();   // x2 + thr staging visible

    // lane-split feed: lane ln loads quarter (ln&15) of row jbase+(ln>>4);
    // one float4 load per lane = one 4-j chunk per wave. chunk stride = 256 f.
    const int jbase = q * JW;
    const float* gsrc = hs + (size_t)(jbase + (ln >> 4)) * ND + (ln & 15) * 4;

    float dist[KK]; int idx[KK];
    float4 bA = *(const float4*)(gsrc);
    float4 bB = *(const float4*)(gsrc + 256);

    // ---- peel: chunks 0..3 (j 0..15) -> direct store, then stable sort ----
    #pragma unroll
    for (int c = 0; c < 4; c += 2) {
        #pragma unroll
        for (int rj = 0; rj < 4; ++rj) {
            float dv = dotj(bA, rj * 16, A);
            float d2 = fmaf(-2.f, dv, x2i + ldsx2[jbase + c * 4 + rj]);
            dist[c * 4 + rj] = d2; idx[c * 4 + rj] = jbase + c * 4 + rj;
        }
        bA = *(const float4*)(gsrc + (c + 2) * 256);
        #pragma unroll
        for (int rj = 0; rj < 4; ++rj) {
            float dv = dotj(bB, rj * 16, A);
            float d2 = fmaf(-2.f, dv, x2i + ldsx2[jbase + (c + 1) * 4 + rj]);
            dist[(c + 1) * 4 + rj] = d2; idx[(c + 1) * 4 + rj] = jbase + (c + 1) * 4 + rj;
        }
        bB = *(const float4*)(gsrc + (c + 3) * 256);
    }
    sort16(dist, idx);
    ldsthr[ln] = fminf(ldsthr[ln], dist[KK - 1]);   // benign min-race

    int cnt = 0;
    auto drain = [&]() {
        #pragma unroll 1
        for (int k = 0; k < BUF; ++k) {
            if (!__any(k < cnt)) break;
            bool  act = k < cnt;
            float dd  = pbufd[k * NT + t];
            int   dj  = pbufi[k * NT + t];
            insert16(dist, idx, act ? dd : FLT_MAX, dj);
        }
        cnt = 0;
        ldsthr[ln] = fminf(ldsthr[ln], dist[KK - 1]);
    };

    // ---- main loop: chunks 4..63, double-buffered VMEM feed ----
    for (int c = 4; c < NCH; c += 2) {
        float thrC = ldsthr[ln];
        #pragma unroll
        for (int rj = 0; rj < 4; ++rj) {
            float dv = dotj(bA, rj * 16, A);
            float d2 = fmaf(-2.f, dv, x2i + ldsx2[jbase + c * 4 + rj]);
            float lim = fminf(dist[KK - 1], thrC);
            pbufd[cnt * NT + t] = d2;
            pbufi[cnt * NT + t] = jbase + c * 4 + rj;
            cnt += (d2 < lim) ? 1 : 0;
            if (__any(cnt == BUF)) { drain(); thrC = ldsthr[ln]; }
        }
        bA = *(const float4*)(gsrc + ((c + 2 < NCH) ? (c + 2) : (NCH - 1)) * 256);
        #pragma unroll
        for (int rj = 0; rj < 4; ++rj) {
            float dv = dotj(bB, rj * 16, A);
            float d2 = fmaf(-2.f, dv, x2i + ldsx2[jbase + (c + 1) * 4 + rj]);
            float lim = fminf(dist[KK - 1], thrC);
            pbufd[cnt * NT + t] = d2;
            pbufi[cnt * NT + t] = jbase + (c + 1) * 4 + rj;
            cnt += (d2 < lim) ? 1 : 0;
            if (__any(cnt == BUF)) { drain(); thrC = ldsthr[ln]; }
        }
        bB = *(const float4*)(gsrc + ((c + 3 < NCH) ? (c + 3) : (NCH - 1)) * 256);
    }
    drain();

    // ---- 3-level merge tree through LDS (stride-17; aliases push bufs) ----
    __syncthreads();
    float* md = smem;                      // 4 regions x 64 lanes, stride MS
    int*   mi = (int*)(smem + 4352);
    #pragma unroll 1
    for (int lvl = 0; lvl < 3; ++lvl) {
        const int step = 1 << lvl;
        const int m    = (step << 1) - 1;
        const bool pub = (q & m) == step;
        const bool con = (q & m) == 0;
        const int reg  = q >> (lvl + 1);
        if (pub) {
            #pragma unroll
            for (int k = 0; k < KK; ++k) {
                md[(reg * 64 + ln) * MS + k] = dist[k];
                mi[(reg * 64 + ln) * MS + k] = idx[k];
            }
        }
        __syncthreads();
        if (con) {
            #pragma unroll 1
            for (int k = 0; k < KK; ++k)
                insert16(dist, idx, md[(reg * 64 + ln) * MS + k],
                                    mi[(reg * 64 + ln) * MS + k]);
        }
        __syncthreads();
    }

    // ---- output (wave 0 holds the complete list for its 64 rows) ----
    if (q == 0) {
        const int off = s * NP;
        const size_t rg = (size_t)off + row;
        float* o0 = out + rg * KK;
        float* o1 = out + (size_t)NS * NP * KK + rg * KK;
        float* o2 = out + (size_t)2 * NS * NP * KK + rg * KK;
        #pragma unroll
        for (int k = 0; k < KK; ++k) o0[k] = dist[k];
        #pragma unroll
        for (int k = 0; k < KK; ++k) o1[k] = (float)(idx[k] + off);
        #pragma unroll
        for (int k = 0; k < KK; ++k) o2[k] = (float)(off + row);
    }
}

extern "C" void kernel_launch(void* const* d_in, const int* in_sizes, int n_in,
                              void* d_out, int out_size, void* d_ws, size_t ws_size,
                              hipStream_t stream)
{
    const float* h = (const float*)d_in[0];
    float* x2  = (float*)d_ws;            // NS*NP floats = 128 KB scratch
    float* out = (float*)d_out;
    hipLaunchKernelGGL(x2_kernel, dim3(NS * NP / 256), dim3(256), 0, stream, h, x2);
    hipLaunchKernelGGL(knn_main,  dim3(NS * 32),       dim3(NT),  0, stream, h, x2, out);
}

// Round 9
// 250.040 us; speedup vs baseline: 5.4858x; 1.3203x over previous
//
#include <hip/hip_runtime.h>
#include <hip/hip_fp16.h>
#include <cfloat>

// NearestNeighborGraph: S=16, N=2048, D=64, K=16.
// Round-9: MFMA-filtered exact KNN.
//  Pass 1: f16 MFMA (16x16x32) computes approx d2 for all pairs; per-wave
//          LDS scoreboard transpose lets the round-8 push/drain machinery
//          (lane=row) maintain approx top-16 per row.
//  Thr:    merge 4 wave-lists -> exact 16th-smallest approx d2 (u16);
//          tau = u16 + 1.0 (worst-case f16 error ~0.16 -> 6x margin) keeps
//          every true fp32 top-16 member.
//  Pass 2: re-scan with MFMA, direct C-layout filter vs tau (VGPR), push
//          survivors (~19/row, cap 32 = +8sigma) to per-row LDS rings.
//  Rescue: exact fp32 recompute of candidates with the bit-identical
//          round-1 fmaf chains (ascending x2i, rotated x2j) + lex (d2,j)
//          top-16 == reference tie-break -> output identical to rounds 1-8.

typedef _Float16 half8 __attribute__((ext_vector_type(8)));
typedef float    f32x4 __attribute__((ext_vector_type(4)));

constexpr int NS = 16, NP = 2048, ND = 64, KK = 16;
constexpr int NWV = 4;              // waves per block
constexpr int NT  = NWV * 64;       // 256 threads
constexpr int JW  = NP / NWV;       // 512 j per wave
constexpr int NJT = JW / 16;        // 32 j-tiles per wave
constexpr int BUF = 8;              // approx push slots per lane
constexpr int MS  = 17;             // merge-tree stride
constexpr int SCB = 68;             // scoreboard stride ([j][i], b128-aligned)
constexpr int RCAP = 32;            // candidate ring slots per row
constexpr float MARGIN = 1.0f;

// ---- prep: x2 (rotated chain, exact round-1 j-side value) + f16 copy ----
__global__ void prep_kernel(const float* __restrict__ h, float* __restrict__ x2,
                            _Float16* __restrict__ hh)
{
    int g = blockIdx.x * 256 + threadIdx.x;          // global row 0..NS*NP-1
    const float4* row = (const float4*)(h + (size_t)g * ND);
    int ph = g & 15;
    float a0 = 0.f, a1 = 0.f, a2 = 0.f, a3 = 0.f;
    #pragma unroll
    for (int k = 0; k < 16; ++k) {
        float4 v = row[(k + ph) & 15];
        a0 = fmaf(v.x, v.x, a0); a1 = fmaf(v.y, v.y, a1);
        a2 = fmaf(v.z, v.z, a2); a3 = fmaf(v.w, v.w, a3);
    }
    x2[g] = (a0 + a1) + (a2 + a3);
    _Float16* dst = hh + (size_t)g * ND;
    #pragma unroll
    for (int k = 0; k < 8; ++k) {
        float4 v0 = row[2 * k], v1 = row[2 * k + 1];
        half8 p;
        p[0] = (_Float16)v0.x; p[1] = (_Float16)v0.y;
        p[2] = (_Float16)v0.z; p[3] = (_Float16)v0.w;
        p[4] = (_Float16)v1.x; p[5] = (_Float16)v1.y;
        p[6] = (_Float16)v1.z; p[7] = (_Float16)v1.w;
        *(half8*)(dst + k * 8) = p;
    }
}

// plain value insert (approx path: only the 16th VALUE matters)
__device__ __forceinline__ void insert16(float (&d)[KK], int (&ix)[KK],
                                         float v, int j)
{
    #pragma unroll
    for (int p = KK - 1; p > 0; --p) {
        bool sh = v < d[p - 1];
        bool he = v < d[p];
        float nd = sh ? d[p - 1] : (he ? v : d[p]);
        int   ni = sh ? ix[p - 1] : (he ? j : ix[p]);
        d[p] = nd; ix[p] = ni;
    }
    if (v < d[0]) { d[0] = v; ix[0] = j; }
}

// lexicographic (d2, j) insert == top_k tie-break (lowest index on equal d2)
__device__ __forceinline__ bool lexlt(float a, int ja, float b, int jb)
{
    return (a < b) || (a == b && ja < jb);
}
__device__ __forceinline__ void insert16x(float (&d)[KK], int (&ix)[KK],
                                          float v, int j)
{
    #pragma unroll
    for (int p = KK - 1; p > 0; --p) {
        bool sh = lexlt(v, j, d[p - 1], ix[p - 1]);
        bool he = lexlt(v, j, d[p], ix[p]);
        float nd = sh ? d[p - 1] : (he ? v : d[p]);
        int   ni = sh ? ix[p - 1] : (he ? j : ix[p]);
        d[p] = nd; ix[p] = ni;
    }
    if (lexlt(v, j, d[0], ix[0])) { d[0] = v; ix[0] = j; }
}

__global__ __launch_bounds__(NT)
void knn_mfma(const float* __restrict__ h, const _Float16* __restrict__ hh,
              const float* __restrict__ x2g, float* __restrict__ out)
{
    // float-indexed carve, 17088 floats = 68352 B (2 blocks/CU)
    __shared__ __align__(16) float smem[17088];
    float* ldsx2  = smem;                    // [0,2048)
    float* scb    = smem + 2048;             // [2048,6400)  4 waves x 16 x 68
    float* pbufd  = smem + 6400;             // [6400,8448)
    int*   pbufi  = (int*)(smem + 8448);     // [8448,10496)
    float* md     = smem + 10496;            // [10496,12672) 2 x 64 x 17
    int*   mi     = (int*)(smem + 12672);    // [12672,14848)
    float* ldsthr = smem + 14848;            // [14848,14912)
    int*   ring   = (int*)(smem + 14912);    // [14912,17024) 64 x 33
    int*   rcnt   = (int*)(smem + 17024);    // [17024,17088)

    const int t   = threadIdx.x;
    const int ln  = t & 63;
    const int qd  = ln >> 4;                 // quad within wave
    const int cl  = ln & 15;                 // col within quad group
    const int q   = t >> 6;                  // wave id (j-quarter)
    const int s   = blockIdx.x >> 5;
    const int rb  = blockIdx.x & 31;
    const int rowbase = rb * 64;             // block's 64 i-rows (sample-local)
    const float*    __restrict__ hs  = h  + (size_t)s * NP * ND;
    const _Float16* __restrict__ hhs = hh + (size_t)s * NP * ND;

    // stage sample x2; init thr
    ((float4*)ldsx2)[t]       = ((const float4*)(x2g + s * NP))[t];
    ((float4*)ldsx2)[t + 256] = ((const float4*)(x2g + s * NP))[t + 256];
    if (t < 64) { ldsthr[t] = FLT_MAX; rcnt[t] = 0; }

    // A-frags: 4 i-tiles x 2 K-chunks; lane holds A[m=cl][k=qd*8..+7]
    half8 afr[4][2];
    #pragma unroll
    for (int it = 0; it < 4; ++it) {
        const _Float16* ap = hhs + (size_t)(rowbase + it * 16 + cl) * ND + qd * 8;
        afr[it][0] = *(const half8*)(ap);
        afr[it][1] = *(const half8*)(ap + 32);
    }
    __syncthreads();

    // x2i (approx side, rotated values fine) for lane's 16 (it,r) rows
    float x2r[16];
    #pragma unroll
    for (int it = 0; it < 4; ++it)
        #pragma unroll
        for (int r = 0; r < 4; ++r)
            x2r[it * 4 + r] = ldsx2[rowbase + it * 16 + qd * 4 + r];

    float dist[KK]; int idx[KK];
    #pragma unroll
    for (int k = 0; k < KK; ++k) { dist[k] = FLT_MAX; idx[k] = 0; }

    const int jbase = q * JW;
    float* scbW = scb + q * (16 * SCB);

    int cnt = 0;
    auto drain = [&]() {
        #pragma unroll 1
        for (int k = 0; k < BUF; ++k) {
            if (!__any(k < cnt)) break;
            bool  act = k < cnt;
            float dd  = pbufd[k * NT + t];
            int   dj  = pbufi[k * NT + t];
            insert16(dist, idx, act ? dd : FLT_MAX, dj);
        }
        cnt = 0;
        ldsthr[ln] = fminf(ldsthr[ln], dist[KK - 1]);   // benign min-race
    };

    // ================= pass 1: MFMA scan + approx top-16 =================
    for (int jt = 0; jt < NJT; ++jt) {
        const int j0 = jbase + jt * 16;
        const _Float16* bp = hhs + (size_t)(j0 + cl) * ND + qd * 8;
        half8 blo = *(const half8*)(bp);
        half8 bhi = *(const half8*)(bp + 32);
        float x2j = ldsx2[j0 + cl];

        f32x4 acc[4];
        #pragma unroll
        for (int it = 0; it < 4; ++it) {
            acc[it] = __builtin_amdgcn_mfma_f32_16x16x32_f16(
                          afr[it][0], blo, (f32x4){0.f, 0.f, 0.f, 0.f}, 0, 0, 0);
            acc[it] = __builtin_amdgcn_mfma_f32_16x16x32_f16(
                          afr[it][1], bhi, acc[it], 0, 0, 0);
        }
        // d2a -> scoreboard [j][i] (b128 per i-tile)
        #pragma unroll
        for (int it = 0; it < 4; ++it) {
            f32x4 w;
            #pragma unroll
            for (int r = 0; r < 4; ++r)
                w[r] = fmaf(-2.f, acc[it][r], x2r[it * 4 + r] + x2j);
            *(f32x4*)(scbW + cl * SCB + it * 16 + qd * 4) = w;
        }
        // lane = row: read own row's 16 scores, push/drain (round-8 style)
        float thrC = ldsthr[ln];
        #pragma unroll
        for (int jj = 0; jj < 16; ++jj) {
            float d2 = scbW[jj * SCB + ln];
            float lim = fminf(dist[KK - 1], thrC);
            pbufd[cnt * NT + t] = d2;
            pbufi[cnt * NT + t] = j0 + jj;
            cnt += (d2 < lim) ? 1 : 0;
            if (__any(cnt == BUF)) { drain(); thrC = ldsthr[ln]; }
        }
    }
    drain();

    // ============ merge approx lists (2 levels) -> tau per row ============
    __syncthreads();
    #pragma unroll 1
    for (int lvl = 0; lvl < 2; ++lvl) {
        const int step = 1 << lvl;
        const int m    = (step << 1) - 1;
        const bool pub = (q & m) == step;
        const bool con = (q & m) == 0;
        const int reg  = q >> (lvl + 1);
        if (pub) {
            #pragma unroll
            for (int k = 0; k < KK; ++k) {
                md[(reg * 64 + ln) * MS + k] = dist[k];
                mi[(reg * 64 + ln) * MS + k] = idx[k];
            }
        }
        __syncthreads();
        if (con) {
            #pragma unroll 1
            for (int k = 0; k < KK; ++k)
                insert16(dist, idx, md[(reg * 64 + ln) * MS + k],
                                    mi[(reg * 64 + ln) * MS + k]);
        }
        __syncthreads();
    }
    if (q == 0) ldsthr[ln] = dist[KK - 1] + MARGIN;   // tau = u16 + margin
    __syncthreads();

    // tau for lane's 16 rows into VGPRs
    float thrv[16];
    #pragma unroll
    for (int it = 0; it < 4; ++it)
        #pragma unroll
        for (int r = 0; r < 4; ++r)
            thrv[it * 4 + r] = ldsthr[it * 16 + qd * 4 + r];
    __syncthreads();

    // ================= pass 2: re-scan, fill candidate rings ==============
    for (int jt = 0; jt < NJT; ++jt) {
        const int j0 = jbase + jt * 16;
        const _Float16* bp = hhs + (size_t)(j0 + cl) * ND + qd * 8;
        half8 blo = *(const half8*)(bp);
        half8 bhi = *(const half8*)(bp + 32);
        float x2j = ldsx2[j0 + cl];

        f32x4 acc[4];
        #pragma unroll
        for (int it = 0; it < 4; ++it) {
            acc[it] = __builtin_amdgcn_mfma_f32_16x16x32_f16(
                          afr[it][0], blo, (f32x4){0.f, 0.f, 0.f, 0.f}, 0, 0, 0);
            acc[it] = __builtin_amdgcn_mfma_f32_16x16x32_f16(
                          afr[it][1], bhi, acc[it], 0, 0, 0);
        }
        #pragma unroll
        for (int it = 0; it < 4; ++it) {
            #pragma unroll
            for (int r = 0; r < 4; ++r) {
                float d2 = fmaf(-2.f, acc[it][r], x2r[it * 4 + r] + x2j);
                if (d2 < thrv[it * 4 + r]) {
                    int rw = it * 16 + qd * 4 + r;
                    int slot = atomicAdd(&rcnt[rw], 1);
                    if (slot < RCAP) ring[rw * 33 + slot] = j0 + cl;
                }
            }
        }
    }
    __syncthreads();

    // ========== rescue: exact fp32 recompute of candidates ===============
    // lane = row ln; wave q handles ring slots q, q+4, ...
    const int myrow = rowbase + ln;
    float4 A[16];
    {
        const float4* ra = (const float4*)(hs + (size_t)myrow * ND);
        #pragma unroll
        for (int k = 0; k < 16; ++k) A[k] = ra[k];
    }
    float x2i;   // ascending chain (exact round-1 i-side value)
    {
        float a0 = 0.f, a1 = 0.f, a2 = 0.f, a3 = 0.f;
        #pragma unroll
        for (int k = 0; k < 16; ++k) {
            a0 = fmaf(A[k].x, A[k].x, a0); a1 = fmaf(A[k].y, A[k].y, a1);
            a2 = fmaf(A[k].z, A[k].z, a2); a3 = fmaf(A[k].w, A[k].w, a3);
        }
        x2i = (a0 + a1) + (a2 + a3);
    }
    #pragma unroll
    for (int k = 0; k < KK; ++k) { dist[k] = FLT_MAX; idx[k] = 0; }

    const int cntR = min(rcnt[ln], RCAP);
    #pragma unroll 1
    for (int k = q; k < cntR; k += NWV) {
        int j = ring[ln * 33 + k];
        const float4* cv = (const float4*)(hs + (size_t)j * ND);
        float a0 = 0.f, a1 = 0.f, a2 = 0.f, a3 = 0.f;
        #pragma unroll
        for (int kk = 0; kk < 16; ++kk) {
            float4 c = cv[kk];
            a0 = fmaf(A[kk].x, c.x, a0); a1 = fmaf(A[kk].y, c.y, a1);
            a2 = fmaf(A[kk].z, c.z, a2); a3 = fmaf(A[kk].w, c.w, a3);
        }
        float dotv = (a0 + a1) + (a2 + a3);
        float d2 = fmaf(-2.0f, dotv, x2i + ldsx2[j]);
        insert16x(dist, idx, d2, j);
    }

    // ---- final exact merge (lex) across the 4 waves ----
    __syncthreads();
    #pragma unroll 1
    for (int lvl = 0; lvl < 2; ++lvl) {
        const int step = 1 << lvl;
        const int m    = (step << 1) - 1;
        const bool pub = (q & m) == step;
        const bool con = (q & m) == 0;
        const int reg  = q >> (lvl + 1);
        if (pub) {
            #pragma unroll
            for (int k = 0; k < KK; ++k) {
                md[(reg * 64 + ln) * MS + k] = dist[k];
                mi[(reg * 64 + ln) * MS + k] = idx[k];
            }
        }
        __syncthreads();
        if (con) {
            #pragma unroll 1
            for (int k = 0; k < KK; ++k)
                insert16x(dist, idx, md[(reg * 64 + ln) * MS + k],
                                     mi[(reg * 64 + ln) * MS + k]);
        }
        __syncthreads();
    }

    // ---- output (wave 0) ----
    if (q == 0) {
        const int off = s * NP;
        const size_t rg = (size_t)off + myrow;
        float* o0 = out + rg * KK;
        float* o1 = out + (size_t)NS * NP * KK + rg * KK;
        float* o2 = out + (size_t)2 * NS * NP * KK + rg * KK;
        #pragma unroll
        for (int k = 0; k < KK; ++k) o0[k] = dist[k];
        #pragma unroll
        for (int k = 0; k < KK; ++k) o1[k] = (float)(idx[k] + off);
        #pragma unroll
        for (int k = 0; k < KK; ++k) o2[k] = (float)(off + myrow);
    }
}

extern "C" void kernel_launch(void* const* d_in, const int* in_sizes, int n_in,
                              void* d_out, int out_size, void* d_ws, size_t ws_size,
                              hipStream_t stream)
{
    const float* h = (const float*)d_in[0];
    float* out = (float*)d_out;
    float*    x2 = (float*)d_ws;                     // 32768 floats (128 KB)
    _Float16* hh = (_Float16*)(x2 + NS * NP);        // 16*2048*64 halves (4 MB)

    hipLaunchKernelGGL(prep_kernel, dim3(NS * NP / 256), dim3(256), 0, stream,
                       h, x2, hh);
    hipLaunchKernelGGL(knn_mfma, dim3(NS * 32), dim3(NT), 0, stream,
                       h, hh, x2, out);
}